// Round 5
// baseline (494.224 us; speedup 1.0000x reference)
//
#include <hip/hip_runtime.h>

typedef unsigned short u16;
typedef unsigned int u32;
typedef __attribute__((ext_vector_type(8))) short short8;   // 8 x bf16
typedef __attribute__((ext_vector_type(4))) float f32x4;

// ---------------- workspace layout (bytes) ----------------
#define OFF_WM    0         // float[801]: wmean[0..799] (pad 0), [800]=mean(b_in)
#define OFF_WINF  3584      // u16 [25][8][64][8]  W_in B-fragment-linear   (204800 B)
#define OFF_WEGF  208384    // u16 [6][17][64][8]  experts+gate frag-linear (104448 B)
#define OFF_WCTXF 312832    // u16 [2][8][64][8]   W_ctx frag-linear        (16384 B)
#define OFF_WOUTF 329216    // u16 [4][64][8]      W_out frag-linear        (4096 B)

__device__ __forceinline__ u16 f2bf(float x) {
  union { float f; u32 u; } v; v.f = x;
  u32 r = v.u + 0x7FFFu + ((v.u >> 16) & 1u);   // RNE
  return (u16)(r >> 16);
}
__device__ __forceinline__ float bf2f(u16 h) {
  union { u32 u; float f; } v; v.u = ((u32)h) << 16;
  return v.f;
}

// ------------------------------------------------------------------
// Prep: wmean for the exact fp32 t path; all weights -> bf16 in
// MFMA-B-fragment-linear order: frag[tile][lane][j] with
// k = kt*32 + (lane>>4)*8 + j, n = ct*16 + (lane&15).
// ------------------------------------------------------------------
__global__ void prep_kernel(const float* __restrict__ W_in, const float* __restrict__ b_in,
                            const float* __restrict__ W_gate, const float* __restrict__ W_exp,
                            const float* __restrict__ W_ctx, const float* __restrict__ W_out,
                            float* __restrict__ wm, u16* __restrict__ WinF,
                            u16* __restrict__ WegF, u16* __restrict__ WctxF,
                            u16* __restrict__ WoutF) {
  int idx = blockIdx.x * 256 + threadIdx.x;
  if (idx < 801) {
    if (idx == 800) {
      float s = 0.f;
      for (int j = 0; j < 128; ++j) s += b_in[j];
      wm[800] = s * (1.f / 128.f);
    } else if (idx >= 784) {
      wm[idx] = 0.f;
    } else {
      float s = 0.f;
      for (int j = 0; j < 128; ++j) s += W_in[idx * 128 + j];
      wm[idx] = s * (1.f / 128.f);
    }
  } else if (idx < 103201) {                    // WinF: 25*8 tiles
    int f = idx - 801;
    int j = f & 7, lane = (f >> 3) & 63, tile = f >> 9;
    int ct = tile & 7, kt = tile >> 3;
    int k = kt * 32 + ((lane >> 4) << 3) + j;
    int n = ct * 16 + (lane & 15);
    WinF[f] = (k < 784) ? f2bf(W_in[k * 128 + n]) : (u16)0;
  } else if (idx < 155425) {                    // WegF: 6*17 tiles
    int f = idx - 103201;
    int j = f & 7, lane = (f >> 3) & 63, tile = f >> 9;
    int kt = tile / 17, ct = tile - kt * 17;
    int k = kt * 32 + ((lane >> 4) << 3) + j;
    int n = ct * 16 + (lane & 15);
    float v = 0.f;
    if (n < 256) { int e = n >> 6, h = n & 63; v = W_exp[(e * 192 + k) * 64 + h]; }
    else if (n < 260) v = W_gate[k * 4 + (n - 256)];
    WegF[f] = f2bf(v);
  } else if (idx < 163617) {                    // WctxF: 2*8 tiles
    int f = idx - 155425;
    int j = f & 7, lane = (f >> 3) & 63, tile = f >> 9;
    int ct = tile & 7, kt = tile >> 3;
    int k = kt * 32 + ((lane >> 4) << 3) + j;
    int n = ct * 16 + (lane & 15);
    WctxF[f] = f2bf(W_ctx[k * 128 + n]);
  } else if (idx < 165665) {                    // WoutF: 4 tiles (N padded 3->16)
    int f = idx - 163617;
    int j = f & 7, lane = (f >> 3) & 63, kt = f >> 9;
    int k = kt * 32 + ((lane >> 4) << 3) + j;
    int n = lane & 15;
    WoutF[f] = (n < 3) ? f2bf(W_out[k * 3 + n]) : (u16)0;
  }
}

// ------------------------------------------------------------------
// Fused forward, split-K wave pairs: WG = 4 waves = 2 row-groups x 2 members.
// Group g owns 16 rows; member m does kt = m, m+2, ... (phase 1) and
// experts {2m, 2m+1} (phase 2). 3 barriers total. 2048 WGs -> up to 6 WGs/CU
// (VGPR-capped at 85 via launch_bounds(256,6)), 24 waves/CU vs r2's 16.
//
// Per-group LDS region R (4864 u16 = 9728 B), time-multiplexed:
//   exA  fp32 [64][32]  acc exchange            (u16 [0,4096))     phase 1
//   exT  fp32 [64]      t-partial exchange      (u16 [4096,4224))  phase 1
//   enh  bf16 [6][16][40]                       (u16 [0,3840))     ph 1->2
//   exC  bf16 [64][16]  cmb partial exchange    (u16 [3840,4864))  phase 2
//   cmbB bf16 [2][16][40]                       (u16 [0,1280))     ph 2->3
//   ctxB bf16 [16][136]                         (u16 [1280,3456))  ph 3->4
// Same-wave DS ops execute in program order -> intra-wave aliasing is safe;
// cross-wave handoffs are separated by __syncthreads().
// ------------------------------------------------------------------
__global__ __launch_bounds__(256, 6)
void fused_kernel(const float* __restrict__ x,
                  const float* __restrict__ b_in, const float* __restrict__ b_gate,
                  const float* __restrict__ b_exp, const float* __restrict__ b_ctx,
                  const float* __restrict__ b_out,
                  const float* __restrict__ wm, const u16* __restrict__ WinF,
                  const u16* __restrict__ WegF, const u16* __restrict__ WctxF,
                  const u16* __restrict__ WoutF,
                  float* __restrict__ out) {
  __shared__ __align__(16) u16 smem[9728];
  const int tid = threadIdx.x;
  const int wv = tid >> 6;
  const int ln = tid & 63;
  const int cb = ln & 15;        // fragment col / A-row
  const int qr = ln >> 4;        // k-quad
  const int g  = wv >> 1;        // row-group within WG
  const int m  = wv & 1;         // split-K member
  u16* R = smem + g * 4864;
  float* exA = (float*)R;        // [64][32]
  float* exT = (float*)R + 2048; // [64]
  u16* enh  = R;                 // [6][16][40]
  u16* exC  = R + 3840;          // [64][16]
  u16* cmbB = R;                 // [2][16][40]
  u16* ctxB = R + 1280;          // [16][136]

  const int grow = blockIdx.x * 32 + g * 16;      // this group's first row
  const float* xr = x + (size_t)(grow + cb) * 784;

  const f32x4 vz = {0.f, 0.f, 0.f, 0.f};

  // ---- Phase 1: projected = x @ W_in (MFMA) + exact fp32 t; K split 2-way ----
  f32x4 acc[8];
  #pragma unroll
  for (int i = 0; i < 8; ++i) acc[i] = vz;
  float tp = 0.f;

  #pragma unroll
  for (int j = 0; j < 13; ++j) {
    const int kt = 2 * j + m;
    if (kt < 25) {                       // wave-uniform guard (m is uniform)
      const int k0 = kt * 32 + qr * 8;
      // K-tail clamp: garbage x is harmless (WinF rows k>=784 are zero and
      // wm[784..799]==0; wm is loaded at the TRUE k0).
      const int k0c = (k0 <= 776) ? k0 : 776;
      float4 a0 = *(const float4*)(xr + k0c);
      float4 a1 = *(const float4*)(xr + k0c + 4);
      const float4 m0 = *(const float4*)(wm + k0);
      const float4 m1 = *(const float4*)(wm + k0 + 4);
      tp += a0.x * m0.x + a0.y * m0.y + a0.z * m0.z + a0.w * m0.w
          + a1.x * m1.x + a1.y * m1.y + a1.z * m1.z + a1.w * m1.w;
      union { short8 s; u32 u[4]; } af;
      af.u[0] = (u32)f2bf(a0.x) | ((u32)f2bf(a0.y) << 16);
      af.u[1] = (u32)f2bf(a0.z) | ((u32)f2bf(a0.w) << 16);
      af.u[2] = (u32)f2bf(a1.x) | ((u32)f2bf(a1.y) << 16);
      af.u[3] = (u32)f2bf(a1.z) | ((u32)f2bf(a1.w) << 16);
      const u16* wb = WinF + (size_t)kt * 4096 + ln * 8;
      #pragma unroll
      for (int ct = 0; ct < 8; ++ct) {
        short8 Bf = *(const short8*)(wb + ct * 512);
        acc[ct] = __builtin_amdgcn_mfma_f32_16x16x32_bf16(af.s, Bf, acc[ct], 0, 0, 0);
      }
    }
  }

  // exchange member1 -> member0 (fp32, exact)
  if (m == 1) {
    #pragma unroll
    for (int ct = 0; ct < 8; ++ct)
      *(f32x4*)(exA + ln * 32 + ct * 4) = acc[ct];
    exT[ln] = tp;
  }
  __syncthreads();                                   // barrier 1
  if (m == 0) {
    #pragma unroll
    for (int ct = 0; ct < 8; ++ct) {
      f32x4 o = *(const f32x4*)(exA + ln * 32 + ct * 4);
      #pragma unroll
      for (int i = 0; i < 4; ++i) acc[ct][i] += o[i];
    }
    tp += exT[ln];
    tp += __shfl_xor(tp, 16);
    tp += __shfl_xor(tp, 32);
    const float t = tp + wm[800];

    // enhanced[cols 0..127] = projected + b_in  (bf16, chunked [6][16][40])
    #pragma unroll
    for (int ct = 0; ct < 8; ++ct) {
      float bi = b_in[ct * 16 + cb];
      u16* dst = enh + (ct >> 1) * 640 + (ct & 1) * 16 + cb;
      #pragma unroll
      for (int i = 0; i < 4; ++i)
        dst[(qr * 4 + i) * 40] = f2bf(acc[ct][i] + bi);
    }
    // enhanced[cols 128..191] = phasor bank; lane (qr,cb): row cb,
    // harmonics qr*8+1..qr*8+8 via rotation recurrence.
    {
      float phi = 7.f * t;
      float ss, cc, sd, cd;
      sincosf(phi * (float)(qr * 8 + 1), &ss, &cc);
      sincosf(phi, &sd, &cd);
      u16* pc = enh + 4 * 640 + cb * 40 + qr * 8;
      u16* ps = enh + 5 * 640 + cb * 40 + qr * 8;
      #pragma unroll
      for (int h = 0; h < 8; ++h) {
        pc[h] = f2bf(cc);
        ps[h] = f2bf(ss);
        float nc = cc * cd - ss * sd;
        ss = ss * cd + cc * sd;
        cc = nc;
      }
    }
  }
  __syncthreads();                                   // barrier 2

  // ---- Phase 2: gate (both members) + experts {2m,2m+1}, K=192 ----
  f32x4 accg = vz;
  #pragma unroll
  for (int kt = 0; kt < 6; ++kt) {
    short8 Af = *(const short8*)(enh + kt * 640 + cb * 40 + qr * 8);
    short8 Bf = *(const short8*)(WegF + ((kt * 17 + 16) * 64 + ln) * 8);
    accg = __builtin_amdgcn_mfma_f32_16x16x32_bf16(Af, Bf, accg, 0, 0, 0);
  }
  float ge2[2][4];                       // gate weights for this member's experts
  {
    float bg = b_gate[cb & 3];
    #pragma unroll
    for (int i = 0; i < 4; ++i) {
      float gi = accg[i] + bg;
      float mx = fmaxf(gi, __shfl_xor(gi, 1));
      mx = fmaxf(mx, __shfl_xor(mx, 2));
      float ev = __expf(gi - mx);
      float sv = ev + __shfl_xor(ev, 1);
      sv += __shfl_xor(sv, 2);
      float gg = ev / sv;
      int base = qr * 16 + 2 * m;
      ge2[0][i] = __shfl(gg, base);
      ge2[1][i] = __shfl(gg, base + 1);
    }
  }
  f32x4 cmbp[4];
  #pragma unroll
  for (int i = 0; i < 4; ++i) cmbp[i] = vz;
  #pragma unroll
  for (int e2 = 0; e2 < 2; ++e2) {
    const int e = 2 * m + e2;
    f32x4 ae[4];
    #pragma unroll
    for (int i = 0; i < 4; ++i) ae[i] = vz;
    #pragma unroll
    for (int kt = 0; kt < 6; ++kt) {
      short8 Af = *(const short8*)(enh + kt * 640 + cb * 40 + qr * 8);
      #pragma unroll
      for (int c2 = 0; c2 < 4; ++c2) {
        short8 Bf = *(const short8*)(WegF + ((kt * 17 + e * 4 + c2) * 64 + ln) * 8);
        ae[c2] = __builtin_amdgcn_mfma_f32_16x16x32_bf16(Af, Bf, ae[c2], 0, 0, 0);
      }
    }
    #pragma unroll
    for (int c2 = 0; c2 < 4; ++c2) {
      float be = b_exp[e * 64 + c2 * 16 + cb];
      #pragma unroll
      for (int i = 0; i < 4; ++i)
        cmbp[c2][i] += ge2[e2][i] * fmaxf(ae[c2][i] + be, 0.f);
    }
  }
  // exchange member1 partial (bf16; exC is disjoint from enh -> no extra barrier)
  if (m == 1) {
    union { short8 s; u16 h[8]; } p0, p1;
    #pragma unroll
    for (int i = 0; i < 4; ++i) {
      p0.h[i]     = f2bf(cmbp[0][i]);
      p0.h[4 + i] = f2bf(cmbp[1][i]);
      p1.h[i]     = f2bf(cmbp[2][i]);
      p1.h[4 + i] = f2bf(cmbp[3][i]);
    }
    *(short8*)(exC + ln * 16)     = p0.s;
    *(short8*)(exC + ln * 16 + 8) = p1.s;
  }
  __syncthreads();                                   // barrier 3 (last)
  if (m == 1) return;                                // member1 done

  {
    short8 q0 = *(const short8*)(exC + ln * 16);
    short8 q1 = *(const short8*)(exC + ln * 16 + 8);
    #pragma unroll
    for (int c2 = 0; c2 < 4; ++c2) {
      u16* dst = cmbB + (c2 >> 1) * 640 + (c2 & 1) * 16 + cb;
      #pragma unroll
      for (int i = 0; i < 4; ++i) {
        int idx = c2 * 4 + i;
        u16 h = (idx < 8) ? (u16)q0[idx] : (u16)q1[idx - 8];
        dst[(qr * 4 + i) * 40] = f2bf(cmbp[c2][i] + bf2f(h));
      }
    }
  }

  // ---- Phase 3: ctx = tanh(combined @ W_ctx + b_ctx), K=64 ----
  f32x4 acc3[8];
  #pragma unroll
  for (int i = 0; i < 8; ++i) acc3[i] = vz;
  #pragma unroll
  for (int kt = 0; kt < 2; ++kt) {
    short8 Af = *(const short8*)(cmbB + kt * 640 + cb * 40 + qr * 8);
    #pragma unroll
    for (int ct = 0; ct < 8; ++ct) {
      short8 Bf = *(const short8*)(WctxF + ((kt * 8 + ct) * 64 + ln) * 8);
      acc3[ct] = __builtin_amdgcn_mfma_f32_16x16x32_bf16(Af, Bf, acc3[ct], 0, 0, 0);
    }
  }
  #pragma unroll
  for (int ct = 0; ct < 8; ++ct) {
    float bc = b_ctx[ct * 16 + cb];
    u16* dst = ctxB + ct * 16 + cb;
    #pragma unroll
    for (int i = 0; i < 4; ++i) {
      float v = acc3[ct][i] + bc;
      float ex = __expf(2.f * v);          // tanh via exp; saturates correctly
      dst[(qr * 4 + i) * 136] = f2bf(1.f - 2.f / (ex + 1.f));
    }
  }

  // ---- Phase 4: logits = ctx @ W_out + b_out (MFMA, N padded to 16) ----
  f32x4 acc4 = vz;
  #pragma unroll
  for (int kt = 0; kt < 4; ++kt) {
    short8 Af = *(const short8*)(ctxB + cb * 136 + kt * 32 + qr * 8);
    short8 Bf = *(const short8*)(WoutF + (kt * 64 + ln) * 8);
    acc4 = __builtin_amdgcn_mfma_f32_16x16x32_bf16(Af, Bf, acc4, 0, 0, 0);
  }
  if (cb < 3) {
    float bo = b_out[cb];
    #pragma unroll
    for (int i = 0; i < 4; ++i)
      out[(size_t)(grow + qr * 4 + i) * 3 + cb] = acc4[i] + bo;
  }
}

extern "C" void kernel_launch(void* const* d_in, const int* in_sizes, int n_in,
                              void* d_out, int out_size, void* d_ws, size_t ws_size,
                              hipStream_t stream) {
  const float* x      = (const float*)d_in[0];
  const float* W_in   = (const float*)d_in[1];
  const float* b_in   = (const float*)d_in[2];
  const float* W_gate = (const float*)d_in[3];
  const float* b_gate = (const float*)d_in[4];
  const float* W_exp  = (const float*)d_in[5];
  const float* b_exp  = (const float*)d_in[6];
  const float* W_ctx  = (const float*)d_in[7];
  const float* b_ctx  = (const float*)d_in[8];
  const float* W_out  = (const float*)d_in[9];
  const float* b_out  = (const float*)d_in[10];
  float* out = (float*)d_out;

  char* ws = (char*)d_ws;
  float* wm  = (float*)(ws + OFF_WM);
  u16* WinF  = (u16*)(ws + OFF_WINF);
  u16* WegF  = (u16*)(ws + OFF_WEGF);
  u16* WctxF = (u16*)(ws + OFF_WCTXF);
  u16* WoutF = (u16*)(ws + OFF_WOUTF);

  const int B = in_sizes[0] / 784;
  prep_kernel<<<648, 256, 0, stream>>>(W_in, b_in, W_gate, W_exp, W_ctx, W_out,
                                       wm, WinF, WegF, WctxF, WoutF);
  fused_kernel<<<B / 32, 256, 0, stream>>>(x, b_in, b_gate, b_exp, b_ctx, b_out,
                                           wm, WinF, WegF, WctxF, WoutF, out);
}